// Round 7
// baseline (677.802 us; speedup 1.0000x reference)
//
#include <hip/hip_runtime.h>
#include <hip/hip_fp16.h>
#include <stdint.h>

#define Bn 8
#define Dd 512
#define Nn 2048

typedef _Float16 f16;
typedef __attribute__((ext_vector_type(8))) _Float16 f16x8;
typedef __attribute__((ext_vector_type(4))) _Float16 f16x4;
typedef __attribute__((ext_vector_type(4))) float f32x4;

// ---- workspace layout (f16 elements), all single-plane f16 ----
#define OFF_W   ((size_t)0)                        // 3 * 262144
#define OFF_XT  ((size_t)786432)                   // x^T [B][N][D]
#define OFF_Q   ((size_t)(786432 + 1*8388608))     // Q [B][N][D]
#define OFF_K   ((size_t)(786432 + 2*8388608))     // K [B][N][D]
#define OFF_VT  ((size_t)(786432 + 3*8388608))     // V^T [B][D][N]
#define OFF_OP  ((size_t)(786432 + 4*8388608))     // opart [S][B][D][N]

static __device__ __forceinline__ f32x4 MFMA16(f16x8 a, f16x8 b, f32x4 c) {
  return __builtin_amdgcn_mfma_f32_16x16x32_f16(a, b, c, 0, 0, 0);
}

// async global->LDS, 16B/lane; lds dest = wave-uniform base + lane*16
static __device__ __forceinline__ void gl16(const f16* g, f16* l) {
  __builtin_amdgcn_global_load_lds(
      (const __attribute__((address_space(1))) void*)(const void*)g,
      (__attribute__((address_space(3))) void*)(void*)l, 16, 0, 0);
}

#define WAITV(n) asm volatile("s_waitcnt vmcnt(" #n ")" ::: "memory")

// ---------------------------------------------------------------------------
__global__ void wcvt_kernel(const float* __restrict__ Wq,
                            const float* __restrict__ Wk,
                            const float* __restrict__ Wv,
                            f16* __restrict__ ws) {
  int idx = blockIdx.x * 256 + threadIdx.x;  // < 786432
  int p = idx >> 18;
  int e = idx & 262143;
  const float* W = (p == 0) ? Wq : ((p == 1) ? Wk : Wv);
  ws[OFF_W + idx] = (f16)W[e];
}

// ---------------------------------------------------------------------------
// transpose x [B][D][N] -> xt [B][N][D], single f16
__global__ void xt_kernel(const float* __restrict__ x, f16* __restrict__ ws) {
  __shared__ float t[32][33];
  int b = blockIdx.z, d0 = blockIdx.y * 32, n0 = blockIdx.x * 32;
  int tid = threadIdx.x;
  int r = tid >> 5, c = tid & 31;
  const float* xb = x + (size_t)b * Dd * Nn;
#pragma unroll
  for (int rr = 0; rr < 4; ++rr) {
    int dl = rr * 8 + r;
    t[dl][c] = xb[(size_t)(d0 + dl) * Nn + n0 + c];
  }
  __syncthreads();
  f16* xt = ws + OFF_XT + (size_t)b * Nn * Dd;
#pragma unroll
  for (int rr = 0; rr < 4; ++rr) {
    int nl = rr * 8 + r;
    xt[(n0 + nl) * Dd + d0 + c] = (f16)t[c][nl];
  }
}

// ---------------------------------------------------------------------------
// projection GEMM, single-pass f16: y = xt*W^T + b. grid (N/64, B, 3).
__global__ __launch_bounds__(256, 2) void proj_kernel(
    f16* __restrict__ ws,
    const float* __restrict__ bq, const float* __restrict__ bk,
    const float* __restrict__ bv) {
  int z = blockIdx.z, b = blockIdx.y, n0 = blockIdx.x * 64;
  const f16* Wp = ws + OFF_W + (size_t)z * 262144;
  const f16* xt = ws + OFF_XT + (size_t)b * Nn * Dd;
  int tid = threadIdx.x;
  int w = tid >> 6, l = tid & 63;
  int l16 = l & 15, lq = l >> 4;
  int j0 = w * 128;

  f32x4 acc[32];
#pragma unroll
  for (int i = 0; i < 32; ++i) acc[i] = (f32x4){0.f, 0.f, 0.f, 0.f};

  for (int ks = 0; ks < 16; ++ks) {
    f16x8 ax[4], bw[8];
#pragma unroll
    for (int rt = 0; rt < 4; ++rt)
      ax[rt] = *(const f16x8*)(xt + (n0 + rt * 16 + l16) * Dd + ks * 32 + lq * 8);
#pragma unroll
    for (int ct = 0; ct < 8; ++ct)
      bw[ct] = *(const f16x8*)(Wp + (j0 + ct * 16 + l16) * Dd + ks * 32 + lq * 8);
#pragma unroll
    for (int ct = 0; ct < 8; ++ct)
#pragma unroll
      for (int rt = 0; rt < 4; ++rt)
        acc[rt * 8 + ct] = MFMA16(ax[rt], bw[ct], acc[rt * 8 + ct]);
  }

  const float* bias = (z == 0) ? bq : ((z == 1) ? bk : bv);
  if (z < 2) {
    f16* Op = ws + ((z == 0) ? OFF_Q : OFF_K) + (size_t)b * Nn * Dd;
#pragma unroll
    for (int ct = 0; ct < 8; ++ct) {
      int j = j0 + ct * 16 + l16;
      float bj = bias[j];
#pragma unroll
      for (int rt = 0; rt < 4; ++rt) {
        f32x4 a = acc[rt * 8 + ct];
#pragma unroll
        for (int r = 0; r < 4; ++r)
          Op[(n0 + rt * 16 + lq * 4 + r) * Dd + j] = (f16)(a[r] + bj);
      }
    }
  } else {
    f16* Vt = ws + OFF_VT + (size_t)b * Dd * Nn;
#pragma unroll
    for (int ct = 0; ct < 8; ++ct) {
      int j = j0 + ct * 16 + l16;
      float bj = bias[j];
#pragma unroll
      for (int rt = 0; rt < 4; ++rt) {
        f32x4 a = acc[rt * 8 + ct];
        f16x4 hv;
#pragma unroll
        for (int r = 0; r < 4; ++r) hv[r] = (f16)(a[r] + bj);
        *(f16x4*)(Vt + (size_t)j * Nn + n0 + rt * 16 + lq * 4) = hv;
      }
    }
  }
}

// ---------------------------------------------------------------------------
// split-K flash attention, 8 waves x 16 q-rows = 128 q-rows/block.
// Grid 128*S (1D), XCD swizzle: 16 blocks sharing a (b,sp) K/V slice are
// contiguous -> one XCD, slice L2-resident. S=2 -> grid 256 = 1 block/CU,
// single round. Counted-vmcnt pipeline: K chunks [64 keys][256 d] double-
// buffered (2 QK phases/kt), V [512][64] staged during previous PV.
// 6 barriers/kt. setprio(1) around MFMA clusters (T5).
// LDS f16: Kbuf[2][16384] @0, V @32768 (32768), P @65536 (8*16*72 = 9216).
// Total 74752 f16 = 149504 B -> 1 block/CU.
#define VO 32768
#define PO 65536

__global__ __launch_bounds__(512, 1) void attn_kernel(
    const f16* __restrict__ ws, f16* __restrict__ opart,
    float* __restrict__ mbuf, float* __restrict__ lbuf, int nkt, int lgS) {
  __shared__ f16 lds[74752];
  const int S = 1 << lgS;
  const int cpx = gridDim.x >> 3;
  const int orig = blockIdx.x;
  const int lid = (orig & 7) * cpx + (orig >> 3);
  const int group = lid >> 4, tile = lid & 15;
  const int b = group >> lgS, sp = group & (S - 1);
  const int n0 = tile * 128;

  const int tid = threadIdx.x;
  const int w = tid >> 6, l = tid & 63;
  const int l16 = l & 15, lq = l >> 4;

  const f16* Q  = ws + OFF_Q  + (size_t)b * Nn * Dd;
  const f16* Kp = ws + OFF_K  + (size_t)b * Nn * Dd;
  const f16* Vt = ws + OFF_VT + (size_t)b * Dd * Nn;
  const int qrow = n0 + w * 16 + l16;
  const int kbase = sp * nkt * 64;

  // K half-tile stage: 64 rows x 256 d = 2048 x 16B slots, 4/thread
#define KSTAGE(kt_, half_, bb_)                                             \
  {                                                                         \
    const int k0s = kbase + (kt_) * 64;                                     \
    _Pragma("unroll") for (int j = 0; j < 4; ++j) {                         \
      const int slot0 = j * 512 + w * 64;                                   \
      const int slot = slot0 + l;                                           \
      const int row = slot >> 5, c = slot & 31;                             \
      const f16* src = Kp + (size_t)(k0s + row) * Dd + (half_) * 256 +      \
                       ((c ^ (row & 7)) << 3);                              \
      gl16(src, (f16*)&lds[(bb_) * 16384 + slot0 * 8]);                     \
    }                                                                       \
  }
  // V stage: 512 rows x 64 keys = 4096 slots, 8/thread
#define VSTAGE(kt_)                                                         \
  {                                                                         \
    const int k0s = kbase + (kt_) * 64;                                     \
    _Pragma("unroll") for (int j = 0; j < 8; ++j) {                         \
      const int slot0 = j * 512 + w * 64;                                   \
      const int slot = slot0 + l;                                           \
      const int d = slot >> 3, c = slot & 7;                                \
      const f16* src = Vt + (size_t)d * Nn + k0s + ((c ^ (d & 7)) << 3);    \
      gl16(src, (f16*)&lds[VO + slot0 * 8]);                                \
    }                                                                       \
  }
  // QK^T on a 256-d half (phase ph_, Kbuf bb_): 32 ds_read + 32 MFMA
#define QKT(ph_, bb_)                                                       \
  __builtin_amdgcn_s_setprio(1);                                            \
  _Pragma("unroll") for (int ks = 0; ks < 8; ++ks) {                        \
    const int swz = (((ks * 4 + lq) ^ (l16 & 7)) << 3);                     \
    f16x8 kb0 = *(const f16x8*)&lds[(bb_) * 16384 + (l16) * 256 + swz];     \
    f16x8 kb1 = *(const f16x8*)&lds[(bb_) * 16384 + (16 + l16) * 256 + swz];\
    f16x8 kb2 = *(const f16x8*)&lds[(bb_) * 16384 + (32 + l16) * 256 + swz];\
    f16x8 kb3 = *(const f16x8*)&lds[(bb_) * 16384 + (48 + l16) * 256 + swz];\
    s4[0] = MFMA16(q[(ph_) * 8 + ks], kb0, s4[0]);                          \
    s4[1] = MFMA16(q[(ph_) * 8 + ks], kb1, s4[1]);                          \
    s4[2] = MFMA16(q[(ph_) * 8 + ks], kb2, s4[2]);                          \
    s4[3] = MFMA16(q[(ph_) * 8 + ks], kb3, s4[3]);                          \
  }                                                                         \
  __builtin_amdgcn_s_setprio(0);

  // Q held in regs
  f16x8 q[16];
#pragma unroll
  for (int ks = 0; ks < 16; ++ks)
    q[ks] = *(const f16x8*)(Q + (size_t)qrow * Dd + ks * 32 + lq * 8);

  f32x4 o[32];
#pragma unroll
  for (int i = 0; i < 32; ++i) o[i] = (f32x4){0.f, 0.f, 0.f, 0.f};
  float m[4], lsum[4];
#pragma unroll
  for (int r = 0; r < 4; ++r) { m[r] = -1e30f; lsum[r] = 0.f; }

  // prologue: issue [K(0,h0) 4, K(0,h1) 4, V(0) 8] = 16 outstanding
  KSTAGE(0, 0, 0);
  KSTAGE(0, 1, 1);
  VSTAGE(0);

  for (int kt = 0; kt < nkt; ++kt) {
    const int ktn = (kt + 1 < nkt) ? kt + 1 : kt;  // uniform ledger on last
    f32x4 s4[4];
#pragma unroll
    for (int ct = 0; ct < 4; ++ct) s4[ct] = (f32x4){0.f, 0.f, 0.f, 0.f};

    // ledger at each wait (oldest->newest):
    // pA: [K(kt,h0) 4, K(kt,h1) 4, V(kt) 8]      WAITV(12) drains K(kt,h0)
    // pB: [K(kt,h1) 4, V(kt) 8, K(+1,h0) 4]      WAITV(12) drains K(kt,h1)
    // PV: [V(kt) 8, K(+1,h0) 4, K(+1,h1) 4]      WAITV(8)  drains V(kt)
    WAITV(12);
    __builtin_amdgcn_s_barrier();
    QKT(0, 0);
    __builtin_amdgcn_s_barrier();
    KSTAGE(ktn, 0, 0);

    WAITV(12);
    __builtin_amdgcn_s_barrier();
    QKT(1, 1);
    __builtin_amdgcn_s_barrier();
    KSTAGE(ktn, 1, 1);

    // ---- online softmax (rows live across 16-lane groups)
    float scl[4];
#pragma unroll
    for (int r = 0; r < 4; ++r) {
      float tm = fmaxf(fmaxf(s4[0][r], s4[1][r]), fmaxf(s4[2][r], s4[3][r]));
      tm = fmaxf(tm, __shfl_xor(tm, 1, 16));
      tm = fmaxf(tm, __shfl_xor(tm, 2, 16));
      tm = fmaxf(tm, __shfl_xor(tm, 4, 16));
      tm = fmaxf(tm, __shfl_xor(tm, 8, 16));
      float mn = fmaxf(m[r], tm);
      scl[r] = __expf(m[r] - mn);
      float ps = 0.f;
#pragma unroll
      for (int ct = 0; ct < 4; ++ct) {
        float p2 = __expf(s4[ct][r] - mn);
        s4[ct][r] = p2;
        ps += p2;
      }
      ps += __shfl_xor(ps, 1, 16);
      ps += __shfl_xor(ps, 2, 16);
      ps += __shfl_xor(ps, 4, 16);
      ps += __shfl_xor(ps, 8, 16);
      lsum[r] = lsum[r] * scl[r] + ps;
      m[r] = mn;
    }
#pragma unroll
    for (int i = 0; i < 32; ++i) {
      f32x4 t = o[i];
      t[0] *= scl[0]; t[1] *= scl[1]; t[2] *= scl[2]; t[3] *= scl[3];
      o[i] = t;
    }
    // P -> per-wave-private LDS (same-wave visibility via lgkmcnt only)
#pragma unroll
    for (int ct = 0; ct < 4; ++ct)
#pragma unroll
      for (int r = 0; r < 4; ++r)
        lds[PO + w * 1152 + (lq * 4 + r) * 72 + ct * 16 + l16] =
            (f16)s4[ct][r];
    asm volatile("s_waitcnt lgkmcnt(0)" ::: "memory");

    // ---- PV from LDS V
    WAITV(8);                      // own V slots landed
    __builtin_amdgcn_s_barrier();  // everyone's V slots landed
    __builtin_amdgcn_s_setprio(1);
#pragma unroll
    for (int kks = 0; kks < 2; ++kks) {
      f16x8 pa =
          *(const f16x8*)&lds[PO + w * 1152 + l16 * 72 + kks * 32 + lq * 8];
      const int vswz = (((kks * 4 + lq) ^ (l16 & 7)) << 3);
#pragma unroll
      for (int i = 0; i < 32; ++i) {
        f16x8 vb = *(const f16x8*)&lds[VO + (i * 16 + l16) * 64 + vswz];
        o[i] = MFMA16(pa, vb, o[i]);
      }
    }
    __builtin_amdgcn_s_setprio(0);
    __builtin_amdgcn_s_barrier();  // all waves done reading V(kt)
    VSTAGE(ktn);                   // 8 loads -> steady-state ledger
  }

  // ---- epilogue: drain stray stages (they write LDS), then store
  WAITV(0);
  f16* opb = opart + ((size_t)sp * Bn + b) * Dd * Nn;
  const int nbase = n0 + w * 16 + lq * 4;
#pragma unroll
  for (int i = 0; i < 32; ++i) {
    const int d = i * 16 + l16;
    f16x4 hv;
#pragma unroll
    for (int r = 0; r < 4; ++r) hv[r] = (f16)o[i][r];
    *(f16x4*)(opb + (size_t)d * Nn + nbase) = hv;
  }
  if (l16 == 0) {
    size_t msl = ((size_t)sp * Bn + b) * Nn;
#pragma unroll
    for (int r = 0; r < 4; ++r) {
      mbuf[msl + nbase + r] = m[r];
      lbuf[msl + nbase + r] = lsum[r];
    }
  }
#undef KSTAGE
#undef VSTAGE
#undef QKT
}

// ---------------------------------------------------------------------------
template <int S>
__global__ __launch_bounds__(256) void merge_kernel(
    const f16* __restrict__ opart, const float* __restrict__ mbuf,
    const float* __restrict__ lbuf, float* __restrict__ out) {
  int idx = blockIdx.x * 256 + threadIdx.x;   // < B*D*N/8
  int nb = (idx & 255) * 8;
  int d = (idx >> 8) & 511;
  int b = idx >> 17;

  float ms[2 > S ? 2 : S][8], ls[2 > S ? 2 : S][8];
#pragma unroll
  for (int s = 0; s < S; ++s) {
    const float* mp = mbuf + ((size_t)s * Bn + b) * Nn + nb;
    const float* lp = lbuf + ((size_t)s * Bn + b) * Nn + nb;
    f32x4 a0 = *(const f32x4*)mp, a1 = *(const f32x4*)(mp + 4);
    f32x4 c0 = *(const f32x4*)lp, c1 = *(const f32x4*)(lp + 4);
#pragma unroll
    for (int j = 0; j < 4; ++j) {
      ms[s][j] = a0[j]; ms[s][4 + j] = a1[j];
      ls[s][j] = c0[j]; ls[s][4 + j] = c1[j];
    }
  }
  float M[8], den[8], acc[8];
#pragma unroll
  for (int j = 0; j < 8; ++j) M[j] = ms[0][j];
#pragma unroll
  for (int s = 1; s < S; ++s)
#pragma unroll
    for (int j = 0; j < 8; ++j) M[j] = fmaxf(M[j], ms[s][j]);
#pragma unroll
  for (int j = 0; j < 8; ++j) { den[j] = 0.f; acc[j] = 0.f; }
#pragma unroll
  for (int s = 0; s < S; ++s) {
    const f16* op = opart + (((size_t)s * Bn + b) * Dd + d) * Nn + nb;
    f16x8 ov = *(const f16x8*)op;
#pragma unroll
    for (int j = 0; j < 8; ++j) {
      float wgt = __expf(ms[s][j] - M[j]);
      den[j] += ls[s][j] * wgt;
      acc[j] += (float)ov[j] * wgt;
    }
  }
  float* po = out + ((size_t)b * Dd + d) * Nn + nb;
  f32x4 r0, r1;
#pragma unroll
  for (int j = 0; j < 4; ++j) {
    r0[j] = acc[j] / den[j];
    r1[j] = acc[4 + j] / den[4 + j];
  }
  *(f32x4*)po = r0;
  *(f32x4*)(po + 4) = r1;
}

// ---------------------------------------------------------------------------
extern "C" void kernel_launch(void* const* d_in, const int* in_sizes, int n_in,
                              void* d_out, int out_size, void* d_ws,
                              size_t ws_size, hipStream_t stream) {
  const float* x  = (const float*)d_in[0];
  const float* Wq = (const float*)d_in[1];
  const float* bq = (const float*)d_in[2];
  const float* Wk = (const float*)d_in[3];
  const float* bk = (const float*)d_in[4];
  const float* Wv = (const float*)d_in[5];
  const float* bv = (const float*)d_in[6];
  f16* ws = (f16*)d_ws;
  float* out = (float*)d_out;

  // S=2: grid 256 blocks = exactly 1 block/CU, single round
  int S = 1, lgS = 0;
  {
    size_t need2 = (OFF_OP + 2ull * 8388608) * 2 + 2ull * 131072;
    if (ws_size >= need2) { S = 2; lgS = 1; }
  }
  f16* opart = ws + OFF_OP;
  float* mbuf = (float*)(opart + (size_t)S * 8388608);
  float* lbuf = mbuf + (size_t)S * Bn * Nn;

  hipLaunchKernelGGL(wcvt_kernel, dim3(3072), dim3(256), 0, stream,
                     Wq, Wk, Wv, ws);
  hipLaunchKernelGGL(xt_kernel, dim3(Nn / 32, Dd / 32, Bn), dim3(256), 0,
                     stream, x, ws);
  hipLaunchKernelGGL(proj_kernel, dim3(Nn / 64, Bn, 3), dim3(256), 0, stream,
                     ws, bq, bk, bv);
  hipLaunchKernelGGL(attn_kernel, dim3(128 * S), dim3(512), 0, stream,
                     ws, opart, mbuf, lbuf, 32 / S, lgS);
  if (S == 2) {
    hipLaunchKernelGGL((merge_kernel<2>), dim3(4096), dim3(256), 0, stream,
                       opart, mbuf, lbuf, out);
  } else {
    hipLaunchKernelGGL((merge_kernel<1>), dim3(4096), dim3(256), 0, stream,
                       opart, mbuf, lbuf, out);
  }
}

// Round 8
// 665.530 us; speedup vs baseline: 1.0184x; 1.0184x over previous
//
#include <hip/hip_runtime.h>
#include <hip/hip_fp16.h>
#include <stdint.h>

#define Bn 8
#define Dd 512
#define Nn 2048

typedef _Float16 f16;
typedef __attribute__((ext_vector_type(8))) _Float16 f16x8;
typedef __attribute__((ext_vector_type(4))) _Float16 f16x4;
typedef __attribute__((ext_vector_type(4))) float f32x4;

// ---- workspace layout (f16 elements), all single-plane f16 ----
#define OFF_W   ((size_t)0)                        // 3 * 262144
#define OFF_XT  ((size_t)786432)                   // x^T [B][N][D]
#define OFF_Q   ((size_t)(786432 + 1*8388608))     // Q [B][N][D]
#define OFF_K   ((size_t)(786432 + 2*8388608))     // K [B][N][D]
#define OFF_VT  ((size_t)(786432 + 3*8388608))     // V^T [B][D][N]
#define OFF_OP  ((size_t)(786432 + 4*8388608))     // opart [S][B][D][N]

static __device__ __forceinline__ f32x4 MFMA16(f16x8 a, f16x8 b, f32x4 c) {
  return __builtin_amdgcn_mfma_f32_16x16x32_f16(a, b, c, 0, 0, 0);
}

// async global->LDS, 16B/lane; lds dest = wave-uniform base + lane*16
static __device__ __forceinline__ void gl16(const f16* g, f16* l) {
  __builtin_amdgcn_global_load_lds(
      (const __attribute__((address_space(1))) void*)(const void*)g,
      (__attribute__((address_space(3))) void*)(void*)l, 16, 0, 0);
}

#define WAITV(n) asm volatile("s_waitcnt vmcnt(" #n ")" ::: "memory")

// ---------------------------------------------------------------------------
__global__ void wcvt_kernel(const float* __restrict__ Wq,
                            const float* __restrict__ Wk,
                            const float* __restrict__ Wv,
                            f16* __restrict__ ws) {
  int idx = blockIdx.x * 256 + threadIdx.x;  // < 786432
  int p = idx >> 18;
  int e = idx & 262143;
  const float* W = (p == 0) ? Wq : ((p == 1) ? Wk : Wv);
  ws[OFF_W + idx] = (f16)W[e];
}

// ---------------------------------------------------------------------------
// transpose x [B][D][N] -> xt [B][N][D], single f16
__global__ void xt_kernel(const float* __restrict__ x, f16* __restrict__ ws) {
  __shared__ float t[32][33];
  int b = blockIdx.z, d0 = blockIdx.y * 32, n0 = blockIdx.x * 32;
  int tid = threadIdx.x;
  int r = tid >> 5, c = tid & 31;
  const float* xb = x + (size_t)b * Dd * Nn;
#pragma unroll
  for (int rr = 0; rr < 4; ++rr) {
    int dl = rr * 8 + r;
    t[dl][c] = xb[(size_t)(d0 + dl) * Nn + n0 + c];
  }
  __syncthreads();
  f16* xt = ws + OFF_XT + (size_t)b * Nn * Dd;
#pragma unroll
  for (int rr = 0; rr < 4; ++rr) {
    int nl = rr * 8 + r;
    xt[(n0 + nl) * Dd + d0 + c] = (f16)t[c][nl];
  }
}

// ---------------------------------------------------------------------------
// projection GEMM, single-pass f16: y = xt*W^T + b. grid (N/64, B, 3).
__global__ __launch_bounds__(256, 2) void proj_kernel(
    f16* __restrict__ ws,
    const float* __restrict__ bq, const float* __restrict__ bk,
    const float* __restrict__ bv) {
  int z = blockIdx.z, b = blockIdx.y, n0 = blockIdx.x * 64;
  const f16* Wp = ws + OFF_W + (size_t)z * 262144;
  const f16* xt = ws + OFF_XT + (size_t)b * Nn * Dd;
  int tid = threadIdx.x;
  int w = tid >> 6, l = tid & 63;
  int l16 = l & 15, lq = l >> 4;
  int j0 = w * 128;

  f32x4 acc[32];
#pragma unroll
  for (int i = 0; i < 32; ++i) acc[i] = (f32x4){0.f, 0.f, 0.f, 0.f};

  for (int ks = 0; ks < 16; ++ks) {
    f16x8 ax[4], bw[8];
#pragma unroll
    for (int rt = 0; rt < 4; ++rt)
      ax[rt] = *(const f16x8*)(xt + (n0 + rt * 16 + l16) * Dd + ks * 32 + lq * 8);
#pragma unroll
    for (int ct = 0; ct < 8; ++ct)
      bw[ct] = *(const f16x8*)(Wp + (j0 + ct * 16 + l16) * Dd + ks * 32 + lq * 8);
#pragma unroll
    for (int ct = 0; ct < 8; ++ct)
#pragma unroll
      for (int rt = 0; rt < 4; ++rt)
        acc[rt * 8 + ct] = MFMA16(ax[rt], bw[ct], acc[rt * 8 + ct]);
  }

  const float* bias = (z == 0) ? bq : ((z == 1) ? bk : bv);
  if (z < 2) {
    f16* Op = ws + ((z == 0) ? OFF_Q : OFF_K) + (size_t)b * Nn * Dd;
#pragma unroll
    for (int ct = 0; ct < 8; ++ct) {
      int j = j0 + ct * 16 + l16;
      float bj = bias[j];
#pragma unroll
      for (int rt = 0; rt < 4; ++rt) {
        f32x4 a = acc[rt * 8 + ct];
#pragma unroll
        for (int r = 0; r < 4; ++r)
          Op[(n0 + rt * 16 + lq * 4 + r) * Dd + j] = (f16)(a[r] + bj);
      }
    }
  } else {
    f16* Vt = ws + OFF_VT + (size_t)b * Dd * Nn;
#pragma unroll
    for (int ct = 0; ct < 8; ++ct) {
      int j = j0 + ct * 16 + l16;
      float bj = bias[j];
#pragma unroll
      for (int rt = 0; rt < 4; ++rt) {
        f32x4 a = acc[rt * 8 + ct];
        f16x4 hv;
#pragma unroll
        for (int r = 0; r < 4; ++r) hv[r] = (f16)(a[r] + bj);
        *(f16x4*)(Vt + (size_t)j * Nn + n0 + rt * 16 + lq * 4) = hv;
      }
    }
  }
}

// ---------------------------------------------------------------------------
// split-K flash attention, 4 waves x 16 q-rows = 64 q-rows/block, KVBLK=32.
// Grid 32*B*S (1D), XCD swizzle: 32 blocks sharing a (b,sp) K/V slice are
// lid-contiguous -> one XCD. 1024 blocks at 2 blocks/CU -> ~2 groups live
// per XCD (2 MB working set, R6 geometry). TWO independent barrier domains
// per CU overlap each other's stalls (m114 mechanism).
// Counted-vmcnt ledger/wave: [K(h0)4, K(h1)4, V 8] = 16; waits 12/12/8.
// LDS f16: Kbuf[2][8192] @0, V [512][32] @16384, P 4x16x40 @32768.
// Total 35328 f16 = 70656 B -> 2 blocks/CU.
#define VO 16384
#define PO 32768

__global__ __launch_bounds__(256, 2) void attn_kernel(
    const f16* __restrict__ ws, f16* __restrict__ opart,
    float* __restrict__ mbuf, float* __restrict__ lbuf, int nkt, int lgS) {
  __shared__ f16 lds[35328];
  const int S = 1 << lgS;
  const int cpx = gridDim.x >> 3;
  const int orig = blockIdx.x;
  const int lid = (orig & 7) * cpx + (orig >> 3);
  const int group = lid >> 5, tile = lid & 31;
  const int b = group >> lgS, sp = group & (S - 1);
  const int n0 = tile * 64;

  const int tid = threadIdx.x;
  const int w = tid >> 6, l = tid & 63;
  const int l16 = l & 15, lq = l >> 4;

  const f16* Q  = ws + OFF_Q  + (size_t)b * Nn * Dd;
  const f16* Kp = ws + OFF_K  + (size_t)b * Nn * Dd;
  const f16* Vt = ws + OFF_VT + (size_t)b * Dd * Nn;
  const int qrow = n0 + w * 16 + l16;
  const int kbase = sp * nkt * 32;

  // K half stage: 32 rows x 256 d = 1024 x 16B slots, 4/thread
#define KSTAGE(kt_, half_, bb_)                                             \
  {                                                                         \
    const int k0s = kbase + (kt_) * 32;                                     \
    _Pragma("unroll") for (int j = 0; j < 4; ++j) {                         \
      const int slot0 = j * 256 + w * 64;                                   \
      const int slot = slot0 + l;                                           \
      const int row = slot >> 5, c = slot & 31;                             \
      const f16* src = Kp + (size_t)(k0s + row) * Dd + (half_) * 256 +      \
                       ((c ^ (row & 7)) << 3);                              \
      gl16(src, (f16*)&lds[(bb_) * 8192 + slot0 * 8]);                      \
    }                                                                       \
  }
  // V stage: 512 d-rows x 32 keys = 2048 slots, 8/thread; swz c^((d>>1)&3)
#define VSTAGE(kt_)                                                         \
  {                                                                         \
    const int k0s = kbase + (kt_) * 32;                                     \
    _Pragma("unroll") for (int j = 0; j < 8; ++j) {                         \
      const int slot0 = j * 256 + w * 64;                                   \
      const int slot = slot0 + l;                                           \
      const int d = slot >> 2, c = slot & 3;                                \
      const f16* src = Vt + (size_t)d * Nn + k0s +                          \
                       ((c ^ ((d >> 1) & 3)) << 3);                         \
      gl16(src, (f16*)&lds[VO + slot0 * 8]);                                \
    }                                                                       \
  }
  // QK^T on a 256-d half (phase ph_, Kbuf bb_): 16 ds_read + 16 MFMA
#define QKT(ph_, bb_)                                                       \
  __builtin_amdgcn_s_setprio(1);                                            \
  _Pragma("unroll") for (int ks = 0; ks < 8; ++ks) {                        \
    const int swz = (((ks * 4 + lq) ^ (l16 & 7)) << 3);                     \
    f16x8 kb0 = *(const f16x8*)&lds[(bb_) * 8192 + (l16) * 256 + swz];      \
    f16x8 kb1 = *(const f16x8*)&lds[(bb_) * 8192 + (16 + l16) * 256 + swz]; \
    s4[0] = MFMA16(q[(ph_) * 8 + ks], kb0, s4[0]);                          \
    s4[1] = MFMA16(q[(ph_) * 8 + ks], kb1, s4[1]);                          \
  }                                                                         \
  __builtin_amdgcn_s_setprio(0);

  // Q held in regs
  f16x8 q[16];
#pragma unroll
  for (int ks = 0; ks < 16; ++ks)
    q[ks] = *(const f16x8*)(Q + (size_t)qrow * Dd + ks * 32 + lq * 8);

  f32x4 o[32];
#pragma unroll
  for (int i = 0; i < 32; ++i) o[i] = (f32x4){0.f, 0.f, 0.f, 0.f};
  float m[4], lsum[4];
#pragma unroll
  for (int r = 0; r < 4; ++r) { m[r] = -1e30f; lsum[r] = 0.f; }

  // prologue: [K(0,h0) 4, K(0,h1) 4, V(0) 8] = 16 outstanding / wave
  KSTAGE(0, 0, 0);
  KSTAGE(0, 1, 1);
  VSTAGE(0);

  for (int kt = 0; kt < nkt; ++kt) {
    const int ktn = (kt + 1 < nkt) ? kt + 1 : kt;  // uniform ledger on last
    f32x4 s4[2];
    s4[0] = (f32x4){0.f, 0.f, 0.f, 0.f};
    s4[1] = (f32x4){0.f, 0.f, 0.f, 0.f};

    // ledger (oldest->newest) at each wait:
    // pA: [Kh0 4, Kh1 4, V 8]   WAITV(12) -> Kh0 landed
    // pB: [Kh1 4, V 8, Kn0 4]   WAITV(12) -> Kh1 landed
    // PV: [V 8, Kn0 4, Kn1 4]   WAITV(8)  -> V landed
    WAITV(12);
    __builtin_amdgcn_s_barrier();
    QKT(0, 0);
    __builtin_amdgcn_s_barrier();
    KSTAGE(ktn, 0, 0);

    WAITV(12);
    __builtin_amdgcn_s_barrier();
    QKT(1, 1);
    __builtin_amdgcn_s_barrier();
    KSTAGE(ktn, 1, 1);

    // ---- online softmax with defer-max (T13, THR=8, ballot-uniform)
    float pm[4];
#pragma unroll
    for (int r = 0; r < 4; ++r) {
      float tm = fmaxf(s4[0][r], s4[1][r]);
      tm = fmaxf(tm, __shfl_xor(tm, 1, 16));
      tm = fmaxf(tm, __shfl_xor(tm, 2, 16));
      tm = fmaxf(tm, __shfl_xor(tm, 4, 16));
      tm = fmaxf(tm, __shfl_xor(tm, 8, 16));
      pm[r] = tm;
    }
    bool need = (pm[0] > m[0] + 8.f) || (pm[1] > m[1] + 8.f) ||
                (pm[2] > m[2] + 8.f) || (pm[3] > m[3] + 8.f);
    if (__ballot(need) != 0ull) {
      float scl[4];
#pragma unroll
      for (int r = 0; r < 4; ++r) {
        float mn = fmaxf(m[r], pm[r]);
        scl[r] = __expf(m[r] - mn);
        m[r] = mn;
        lsum[r] *= scl[r];
      }
#pragma unroll
      for (int i = 0; i < 32; ++i) {
        f32x4 t = o[i];
        t[0] *= scl[0]; t[1] *= scl[1]; t[2] *= scl[2]; t[3] *= scl[3];
        o[i] = t;
      }
    }
#pragma unroll
    for (int r = 0; r < 4; ++r) {
      float ps = 0.f;
#pragma unroll
      for (int ct = 0; ct < 2; ++ct) {
        float p2 = __expf(s4[ct][r] - m[r]);
        s4[ct][r] = p2;
        ps += p2;
      }
      ps += __shfl_xor(ps, 1, 16);
      ps += __shfl_xor(ps, 2, 16);
      ps += __shfl_xor(ps, 4, 16);
      ps += __shfl_xor(ps, 8, 16);
      lsum[r] += ps;
    }
    // P -> per-wave-private LDS (row stride 40; same-wave lgkmcnt only)
#pragma unroll
    for (int ct = 0; ct < 2; ++ct)
#pragma unroll
      for (int r = 0; r < 4; ++r)
        lds[PO + w * 640 + (lq * 4 + r) * 40 + ct * 16 + l16] =
            (f16)s4[ct][r];
    asm volatile("s_waitcnt lgkmcnt(0)" ::: "memory");

    // ---- PV from LDS V (32 keys -> single A-fragment)
    WAITV(8);                      // own V slots landed
    __builtin_amdgcn_s_barrier();  // everyone's V slots landed
    {
      f16x8 pa = *(const f16x8*)&lds[PO + w * 640 + l16 * 40 + lq * 8];
      __builtin_amdgcn_s_setprio(1);
#pragma unroll
      for (int i = 0; i < 32; ++i) {
        const int d = i * 16 + l16;
        f16x8 vb = *(const f16x8*)&lds[VO + d * 32 +
                                       ((lq ^ ((d >> 1) & 3)) << 3)];
        o[i] = MFMA16(pa, vb, o[i]);
      }
      __builtin_amdgcn_s_setprio(0);
    }
    __builtin_amdgcn_s_barrier();  // all waves done reading V(kt)
    VSTAGE(ktn);                   // 8 loads -> back to 16 outstanding
  }

  // ---- epilogue: drain stray stages (they write LDS), then store
  WAITV(0);
  f16* opb = opart + ((size_t)sp * Bn + b) * Dd * Nn;
  const int nbase = n0 + w * 16 + lq * 4;
#pragma unroll
  for (int i = 0; i < 32; ++i) {
    const int d = i * 16 + l16;
    f16x4 hv;
#pragma unroll
    for (int r = 0; r < 4; ++r) hv[r] = (f16)o[i][r];
    *(f16x4*)(opb + (size_t)d * Nn + nbase) = hv;
  }
  if (l16 == 0) {
    size_t msl = ((size_t)sp * Bn + b) * Nn;
#pragma unroll
    for (int r = 0; r < 4; ++r) {
      mbuf[msl + nbase + r] = m[r];
      lbuf[msl + nbase + r] = lsum[r];
    }
  }
#undef KSTAGE
#undef VSTAGE
#undef QKT
}

// ---------------------------------------------------------------------------
template <int S>
__global__ __launch_bounds__(256) void merge_kernel(
    const f16* __restrict__ opart, const float* __restrict__ mbuf,
    const float* __restrict__ lbuf, float* __restrict__ out) {
  int idx = blockIdx.x * 256 + threadIdx.x;   // < B*D*N/8
  int nb = (idx & 255) * 8;
  int d = (idx >> 8) & 511;
  int b = idx >> 17;

  float ms[S][8], ls[S][8];
#pragma unroll
  for (int s = 0; s < S; ++s) {
    const float* mp = mbuf + ((size_t)s * Bn + b) * Nn + nb;
    const float* lp = lbuf + ((size_t)s * Bn + b) * Nn + nb;
    f32x4 a0 = *(const f32x4*)mp, a1 = *(const f32x4*)(mp + 4);
    f32x4 c0 = *(const f32x4*)lp, c1 = *(const f32x4*)(lp + 4);
#pragma unroll
    for (int j = 0; j < 4; ++j) {
      ms[s][j] = a0[j]; ms[s][4 + j] = a1[j];
      ls[s][j] = c0[j]; ls[s][4 + j] = c1[j];
    }
  }
  float M[8], den[8], acc[8];
#pragma unroll
  for (int j = 0; j < 8; ++j) M[j] = ms[0][j];
#pragma unroll
  for (int s = 1; s < S; ++s)
#pragma unroll
    for (int j = 0; j < 8; ++j) M[j] = fmaxf(M[j], ms[s][j]);
#pragma unroll
  for (int j = 0; j < 8; ++j) { den[j] = 0.f; acc[j] = 0.f; }
#pragma unroll
  for (int s = 0; s < S; ++s) {
    const f16* op = opart + (((size_t)s * Bn + b) * Dd + d) * Nn + nb;
    f16x8 ov = *(const f16x8*)op;
#pragma unroll
    for (int j = 0; j < 8; ++j) {
      float wgt = __expf(ms[s][j] - M[j]);
      den[j] += ls[s][j] * wgt;
      acc[j] += (float)ov[j] * wgt;
    }
  }
  float* po = out + ((size_t)b * Dd + d) * Nn + nb;
  f32x4 r0, r1;
#pragma unroll
  for (int j = 0; j < 4; ++j) {
    r0[j] = acc[j] / den[j];
    r1[j] = acc[4 + j] / den[4 + j];
  }
  *(f32x4*)po = r0;
  *(f32x4*)(po + 4) = r1;
}

// ---------------------------------------------------------------------------
extern "C" void kernel_launch(void* const* d_in, const int* in_sizes, int n_in,
                              void* d_out, int out_size, void* d_ws,
                              size_t ws_size, hipStream_t stream) {
  const float* x  = (const float*)d_in[0];
  const float* Wq = (const float*)d_in[1];
  const float* bq = (const float*)d_in[2];
  const float* Wk = (const float*)d_in[3];
  const float* bk = (const float*)d_in[4];
  const float* Wv = (const float*)d_in[5];
  const float* bv = (const float*)d_in[6];
  f16* ws = (f16*)d_ws;
  float* out = (float*)d_out;

  int S = 1, lgS = 0;
  {
    size_t need4 = (OFF_OP + 4ull * 8388608) * 2 + 4ull * 131072;
    size_t need2 = (OFF_OP + 2ull * 8388608) * 2 + 2ull * 131072;
    if (ws_size >= need4) { S = 4; lgS = 2; }
    else if (ws_size >= need2) { S = 2; lgS = 1; }
  }
  f16* opart = ws + OFF_OP;
  float* mbuf = (float*)(opart + (size_t)S * 8388608);
  float* lbuf = mbuf + (size_t)S * Bn * Nn;

  hipLaunchKernelGGL(wcvt_kernel, dim3(3072), dim3(256), 0, stream,
                     Wq, Wk, Wv, ws);
  hipLaunchKernelGGL(xt_kernel, dim3(Nn / 32, Dd / 32, Bn), dim3(256), 0,
                     stream, x, ws);
  hipLaunchKernelGGL(proj_kernel, dim3(Nn / 64, Bn, 3), dim3(256), 0, stream,
                     ws, bq, bk, bv);
  // 4-wave blocks, 64 q-rows: grid = (N/64) * B * S = 256*S, KVBLK=32
  hipLaunchKernelGGL(attn_kernel, dim3(256 * S), dim3(256), 0, stream,
                     ws, opart, mbuf, lbuf, 64 / S, lgS);
  switch (S) {
    case 4:
      hipLaunchKernelGGL((merge_kernel<4>), dim3(4096), dim3(256), 0, stream,
                         opart, mbuf, lbuf, out);
      break;
    case 2:
      hipLaunchKernelGGL((merge_kernel<2>), dim3(4096), dim3(256), 0, stream,
                         opart, mbuf, lbuf, out);
      break;
    default:
      hipLaunchKernelGGL((merge_kernel<1>), dim3(4096), dim3(256), 0, stream,
                         opart, mbuf, lbuf, out);
      break;
  }
}

// Round 9
// 419.063 us; speedup vs baseline: 1.6174x; 1.5881x over previous
//
#include <hip/hip_runtime.h>
#include <hip/hip_fp16.h>
#include <stdint.h>

#define Bn 8
#define Dd 512
#define Nn 2048

typedef _Float16 f16;
typedef __attribute__((ext_vector_type(8))) _Float16 f16x8;
typedef __attribute__((ext_vector_type(4))) _Float16 f16x4;
typedef __attribute__((ext_vector_type(4))) float f32x4;

// ---- workspace layout (f16 elements), all single-plane f16 ----
#define OFF_W   ((size_t)0)                        // 3 * 262144
#define OFF_XT  ((size_t)786432)                   // x^T [B][N][D]
#define OFF_Q   ((size_t)(786432 + 1*8388608))     // Q [B][N][D]
#define OFF_K   ((size_t)(786432 + 2*8388608))     // K [B][N][D]
#define OFF_VT  ((size_t)(786432 + 3*8388608))     // V^T [B][D][N]
#define OFF_OP  ((size_t)(786432 + 4*8388608))     // opart [S][B][D][N]

static __device__ __forceinline__ f32x4 MFMA16(f16x8 a, f16x8 b, f32x4 c) {
  return __builtin_amdgcn_mfma_f32_16x16x32_f16(a, b, c, 0, 0, 0);
}

// async global->LDS, 16B/lane; lds dest = wave-uniform base + lane*16
static __device__ __forceinline__ void gl16(const f16* g, f16* l) {
  __builtin_amdgcn_global_load_lds(
      (const __attribute__((address_space(1))) void*)(const void*)g,
      (__attribute__((address_space(3))) void*)(void*)l, 16, 0, 0);
}

#define WAITV(n) asm volatile("s_waitcnt vmcnt(" #n ")" ::: "memory")

// ---------------------------------------------------------------------------
__global__ void wcvt_kernel(const float* __restrict__ Wq,
                            const float* __restrict__ Wk,
                            const float* __restrict__ Wv,
                            f16* __restrict__ ws) {
  int idx = blockIdx.x * 256 + threadIdx.x;  // < 786432
  int p = idx >> 18;
  int e = idx & 262143;
  const float* W = (p == 0) ? Wq : ((p == 1) ? Wk : Wv);
  ws[OFF_W + idx] = (f16)W[e];
}

// ---------------------------------------------------------------------------
// transpose x [B][D][N] -> xt [B][N][D], single f16
__global__ void xt_kernel(const float* __restrict__ x, f16* __restrict__ ws) {
  __shared__ float t[32][33];
  int b = blockIdx.z, d0 = blockIdx.y * 32, n0 = blockIdx.x * 32;
  int tid = threadIdx.x;
  int r = tid >> 5, c = tid & 31;
  const float* xb = x + (size_t)b * Dd * Nn;
#pragma unroll
  for (int rr = 0; rr < 4; ++rr) {
    int dl = rr * 8 + r;
    t[dl][c] = xb[(size_t)(d0 + dl) * Nn + n0 + c];
  }
  __syncthreads();
  f16* xt = ws + OFF_XT + (size_t)b * Nn * Dd;
#pragma unroll
  for (int rr = 0; rr < 4; ++rr) {
    int nl = rr * 8 + r;
    xt[(n0 + nl) * Dd + d0 + c] = (f16)t[c][nl];
  }
}

// ---------------------------------------------------------------------------
// projection GEMM, single-pass f16: y = xt*W^T + b. grid (N/64, B, 3).
__global__ __launch_bounds__(256, 2) void proj_kernel(
    f16* __restrict__ ws,
    const float* __restrict__ bq, const float* __restrict__ bk,
    const float* __restrict__ bv) {
  int z = blockIdx.z, b = blockIdx.y, n0 = blockIdx.x * 64;
  const f16* Wp = ws + OFF_W + (size_t)z * 262144;
  const f16* xt = ws + OFF_XT + (size_t)b * Nn * Dd;
  int tid = threadIdx.x;
  int w = tid >> 6, l = tid & 63;
  int l16 = l & 15, lq = l >> 4;
  int j0 = w * 128;

  f32x4 acc[32];
#pragma unroll
  for (int i = 0; i < 32; ++i) acc[i] = (f32x4){0.f, 0.f, 0.f, 0.f};

  for (int ks = 0; ks < 16; ++ks) {
    f16x8 ax[4], bw[8];
#pragma unroll
    for (int rt = 0; rt < 4; ++rt)
      ax[rt] = *(const f16x8*)(xt + (n0 + rt * 16 + l16) * Dd + ks * 32 + lq * 8);
#pragma unroll
    for (int ct = 0; ct < 8; ++ct)
      bw[ct] = *(const f16x8*)(Wp + (j0 + ct * 16 + l16) * Dd + ks * 32 + lq * 8);
#pragma unroll
    for (int ct = 0; ct < 8; ++ct)
#pragma unroll
      for (int rt = 0; rt < 4; ++rt)
        acc[rt * 8 + ct] = MFMA16(ax[rt], bw[ct], acc[rt * 8 + ct]);
  }

  const float* bias = (z == 0) ? bq : ((z == 1) ? bk : bv);
  if (z < 2) {
    f16* Op = ws + ((z == 0) ? OFF_Q : OFF_K) + (size_t)b * Nn * Dd;
#pragma unroll
    for (int ct = 0; ct < 8; ++ct) {
      int j = j0 + ct * 16 + l16;
      float bj = bias[j];
#pragma unroll
      for (int rt = 0; rt < 4; ++rt) {
        f32x4 a = acc[rt * 8 + ct];
#pragma unroll
        for (int r = 0; r < 4; ++r)
          Op[(n0 + rt * 16 + lq * 4 + r) * Dd + j] = (f16)(a[r] + bj);
      }
    }
  } else {
    f16* Vt = ws + OFF_VT + (size_t)b * Dd * Nn;
#pragma unroll
    for (int ct = 0; ct < 8; ++ct) {
      int j = j0 + ct * 16 + l16;
      float bj = bias[j];
#pragma unroll
      for (int rt = 0; rt < 4; ++rt) {
        f32x4 a = acc[rt * 8 + ct];
        f16x4 hv;
#pragma unroll
        for (int r = 0; r < 4; ++r) hv[r] = (f16)(a[r] + bj);
        *(f16x4*)(Vt + (size_t)j * Nn + n0 + rt * 16 + lq * 4) = hv;
      }
    }
  }
}

// ---------------------------------------------------------------------------
// split-K flash attention, 8 waves x 16 q-rows = 128 q-rows/block.
// Grid 128*S (1D), XCD swizzle. Counted-vmcnt pipeline (R6-verified):
// K chunks [64 keys][128 d] double-buffered, V [512][64] staged during prior
// PV. Waits 10/10/2/2; never 0 in-loop. Defer-max (T13) softmax.
// Epilogue: O transposed through LDS -> full 128B-line opart stores.
// LDS f16: Kbuf[2][8192] @0, V @16384 (32768), P @49152 (8*16*72).
// Total 58368 f16 = 116736 B -> 1 block (8 waves) per CU.
#define VO 16384
#define PO 49152

__global__ __launch_bounds__(512, 2) void attn_kernel(
    const f16* __restrict__ ws, f16* __restrict__ opart,
    float* __restrict__ mbuf, float* __restrict__ lbuf, int nkt, int lgS) {
  __shared__ f16 lds[58368];
  const int S = 1 << lgS;
  const int cpx = gridDim.x >> 3;
  const int orig = blockIdx.x;
  const int lid = (orig & 7) * cpx + (orig >> 3);
  const int group = lid >> 4, tile = lid & 15;
  const int b = group >> lgS, sp = group & (S - 1);
  const int n0 = tile * 128;

  const int tid = threadIdx.x;
  const int w = tid >> 6, l = tid & 63;
  const int l16 = l & 15, lq = l >> 4;

  const f16* Q  = ws + OFF_Q  + (size_t)b * Nn * Dd;
  const f16* Kp = ws + OFF_K  + (size_t)b * Nn * Dd;
  const f16* Vt = ws + OFF_VT + (size_t)b * Dd * Nn;
  const int qrow = n0 + w * 16 + l16;
  const int kbase = sp * nkt * 64;

  // K chunk stage: 64 rows x 128 d = 1024 x 16B slots, 2/thread
#define KSTAGE(kt_, dc_, bb_)                                               \
  {                                                                         \
    const int k0s = kbase + (kt_) * 64;                                     \
    _Pragma("unroll") for (int j = 0; j < 2; ++j) {                         \
      const int slot0 = j * 512 + w * 64;                                   \
      const int slot = slot0 + l;                                           \
      const int row = slot >> 4, c = slot & 15;                             \
      const f16* src = Kp + (size_t)(k0s + row) * Dd + (dc_) * 128 +        \
                       ((c ^ (row & 7)) << 3);                              \
      gl16(src, (f16*)&lds[(bb_) * 8192 + slot0 * 8]);                      \
    }                                                                       \
  }
  // V stage: 512 rows x 64 keys = 4096 slots, 8/thread
#define VSTAGE(kt_)                                                         \
  {                                                                         \
    const int k0s = kbase + (kt_) * 64;                                     \
    _Pragma("unroll") for (int j = 0; j < 8; ++j) {                         \
      const int slot0 = j * 512 + w * 64;                                   \
      const int slot = slot0 + l;                                           \
      const int d = slot >> 3, c = slot & 7;                                \
      const f16* src = Vt + (size_t)d * Nn + k0s + ((c ^ (d & 7)) << 3);    \
      gl16(src, (f16*)&lds[VO + slot0 * 8]);                                \
    }                                                                       \
  }
  // QK^T on a 128-d chunk from Kbuf[bb_]
#define QKT(dc_, bb_)                                                       \
  _Pragma("unroll") for (int ks = 0; ks < 4; ++ks) {                        \
    const int swz = (((ks * 4 + lq) ^ (l16 & 7)) << 3);                     \
    f16x8 kb0 = *(const f16x8*)&lds[(bb_) * 8192 + (l16) * 128 + swz];      \
    f16x8 kb1 = *(const f16x8*)&lds[(bb_) * 8192 + (16 + l16) * 128 + swz]; \
    f16x8 kb2 = *(const f16x8*)&lds[(bb_) * 8192 + (32 + l16) * 128 + swz]; \
    f16x8 kb3 = *(const f16x8*)&lds[(bb_) * 8192 + (48 + l16) * 128 + swz]; \
    s4[0] = MFMA16(q[(dc_) * 4 + ks], kb0, s4[0]);                          \
    s4[1] = MFMA16(q[(dc_) * 4 + ks], kb1, s4[1]);                          \
    s4[2] = MFMA16(q[(dc_) * 4 + ks], kb2, s4[2]);                          \
    s4[3] = MFMA16(q[(dc_) * 4 + ks], kb3, s4[3]);                          \
  }

  // Q held in regs
  f16x8 q[16];
#pragma unroll
  for (int ks = 0; ks < 16; ++ks)
    q[ks] = *(const f16x8*)(Q + (size_t)qrow * Dd + ks * 32 + lq * 8);

  f32x4 o[32];
#pragma unroll
  for (int i = 0; i < 32; ++i) o[i] = (f32x4){0.f, 0.f, 0.f, 0.f};
  float m[4], lsum[4];
#pragma unroll
  for (int r = 0; r < 4; ++r) { m[r] = -1e30f; lsum[r] = 0.f; }

  // prologue: issue order [K0(2), K1(2), V(8)] = 12 outstanding
  KSTAGE(0, 0, 0);
  KSTAGE(0, 1, 1);
  VSTAGE(0);

  for (int kt = 0; kt < nkt; ++kt) {
    const int ktn = (kt + 1 < nkt) ? kt + 1 : kt;  // uniform ledger on last
    f32x4 s4[4];
#pragma unroll
    for (int ct = 0; ct < 4; ++ct) s4[ct] = (f32x4){0.f, 0.f, 0.f, 0.f};

    // ---- 4 QK^T phases; ledger (outstanding oldest->newest at each wait):
    // p0:[K0 2,K1 2,V 8] w10 | p1:[K1 2,V 8,K2 2] w10 | p2:[V 8,K2 2,K3 2] w2
    // p3:[K3 2,Kn0 2] w2
    WAITV(10);
    __builtin_amdgcn_s_barrier();
    QKT(0, 0);
    __builtin_amdgcn_s_barrier();
    KSTAGE(kt, 2, 0);

    WAITV(10);
    __builtin_amdgcn_s_barrier();
    QKT(1, 1);
    __builtin_amdgcn_s_barrier();
    KSTAGE(kt, 3, 1);

    WAITV(2);  // drains V(kt) too (older than K2) — needed by PV anyway
    __builtin_amdgcn_s_barrier();
    QKT(2, 0);
    __builtin_amdgcn_s_barrier();
    KSTAGE(ktn, 0, 0);

    WAITV(2);
    __builtin_amdgcn_s_barrier();
    QKT(3, 1);
    __builtin_amdgcn_s_barrier();
    KSTAGE(ktn, 1, 1);

    // ---- online softmax with defer-max (T13, THR=8, ballot-uniform; R8)
    float pm[4];
#pragma unroll
    for (int r = 0; r < 4; ++r) {
      float tm = fmaxf(fmaxf(s4[0][r], s4[1][r]), fmaxf(s4[2][r], s4[3][r]));
      tm = fmaxf(tm, __shfl_xor(tm, 1, 16));
      tm = fmaxf(tm, __shfl_xor(tm, 2, 16));
      tm = fmaxf(tm, __shfl_xor(tm, 4, 16));
      tm = fmaxf(tm, __shfl_xor(tm, 8, 16));
      pm[r] = tm;
    }
    bool need = (pm[0] > m[0] + 8.f) || (pm[1] > m[1] + 8.f) ||
                (pm[2] > m[2] + 8.f) || (pm[3] > m[3] + 8.f);
    if (__ballot(need) != 0ull) {
      float scl[4];
#pragma unroll
      for (int r = 0; r < 4; ++r) {
        float mn = fmaxf(m[r], pm[r]);
        scl[r] = __expf(m[r] - mn);
        m[r] = mn;
        lsum[r] *= scl[r];
      }
#pragma unroll
      for (int i = 0; i < 32; ++i) {
        f32x4 t = o[i];
        t[0] *= scl[0]; t[1] *= scl[1]; t[2] *= scl[2]; t[3] *= scl[3];
        o[i] = t;
      }
    }
#pragma unroll
    for (int r = 0; r < 4; ++r) {
      float ps = 0.f;
#pragma unroll
      for (int ct = 0; ct < 4; ++ct) {
        float p2 = __expf(s4[ct][r] - m[r]);
        s4[ct][r] = p2;
        ps += p2;
      }
      ps += __shfl_xor(ps, 1, 16);
      ps += __shfl_xor(ps, 2, 16);
      ps += __shfl_xor(ps, 4, 16);
      ps += __shfl_xor(ps, 8, 16);
      lsum[r] += ps;
    }
    // P -> per-wave-private LDS (same-wave visibility via lgkmcnt only)
#pragma unroll
    for (int ct = 0; ct < 4; ++ct)
#pragma unroll
      for (int r = 0; r < 4; ++r)
        lds[PO + w * 1152 + (lq * 4 + r) * 72 + ct * 16 + l16] =
            (f16)s4[ct][r];
    asm volatile("s_waitcnt lgkmcnt(0)" ::: "memory");

    // ---- PV from LDS V (V(kt) guaranteed landed at p2 wait + barrier)
#pragma unroll
    for (int kks = 0; kks < 2; ++kks) {
      f16x8 pa =
          *(const f16x8*)&lds[PO + w * 1152 + l16 * 72 + kks * 32 + lq * 8];
#pragma unroll
      for (int i = 0; i < 32; ++i) {
        f16x8 vb = *(const f16x8*)&lds[VO + (i * 16 + l16) * 64 +
                                       (((kks * 4 + lq) ^ ((i * 16 + l16) & 7))
                                        << 3)];
        o[i] = MFMA16(pa, vb, o[i]);
      }
    }
    __builtin_amdgcn_s_barrier();  // all waves done reading V(kt)
    VSTAGE(ktn);                   // 8 loads -> steady-state ledger
  }

  // ---- epilogue: m,l store; then O transposed through LDS (Kbuf region,
  // dead after WAITV(0)+barrier) in 4 chunks of 128 d; full-line stores.
  WAITV(0);
  if (l16 == 0) {
    size_t msl = ((size_t)sp * Bn + b) * Nn;
    const int nbase = n0 + w * 16 + lq * 4;
#pragma unroll
    for (int r = 0; r < 4; ++r) {
      mbuf[msl + nbase + r] = m[r];
      lbuf[msl + nbase + r] = lsum[r];
    }
  }
  __builtin_amdgcn_s_barrier();  // all waves' stray gl16 writes landed
  {
    f16* opb = opart + ((size_t)sp * Bn + b) * Dd * Nn;
    const int nloc = w * 16 + lq * 4;
#pragma unroll
    for (int cch = 0; cch < 4; ++cch) {
#pragma unroll
      for (int i2 = 0; i2 < 8; ++i2) {
        const int i = cch * 8 + i2;
        const int dloc = i2 * 16 + l16;
        f16x4 hv;
#pragma unroll
        for (int r = 0; r < 4; ++r) hv[r] = (f16)o[i][r];
        *(f16x4*)&lds[dloc * 144 + nloc] = hv;
      }
      __builtin_amdgcn_s_barrier();
#pragma unroll
      for (int it = 0; it < 4; ++it) {
        const int rloc = (tid >> 3) + (it & 1) * 64;
        const int seg = (tid & 7) + (it >> 1) * 8;
        f16x8 vv = *(const f16x8*)&lds[rloc * 144 + seg * 8];
        *(f16x8*)(opb + (size_t)(cch * 128 + rloc) * Nn + n0 + seg * 8) = vv;
      }
      __builtin_amdgcn_s_barrier();
    }
  }
#undef KSTAGE
#undef VSTAGE
#undef QKT
}

// ---------------------------------------------------------------------------
template <int S>
__global__ __launch_bounds__(256) void merge_kernel(
    const f16* __restrict__ opart, const float* __restrict__ mbuf,
    const float* __restrict__ lbuf, float* __restrict__ out) {
  int idx = blockIdx.x * 256 + threadIdx.x;   // < B*D*N/8
  int nb = (idx & 255) * 8;
  int d = (idx >> 8) & 511;
  int b = idx >> 17;

  float ms[S][8], ls[S][8];
#pragma unroll
  for (int s = 0; s < S; ++s) {
    const float* mp = mbuf + ((size_t)s * Bn + b) * Nn + nb;
    const float* lp = lbuf + ((size_t)s * Bn + b) * Nn + nb;
    f32x4 a0 = *(const f32x4*)mp, a1 = *(const f32x4*)(mp + 4);
    f32x4 c0 = *(const f32x4*)lp, c1 = *(const f32x4*)(lp + 4);
#pragma unroll
    for (int j = 0; j < 4; ++j) {
      ms[s][j] = a0[j]; ms[s][4 + j] = a1[j];
      ls[s][j] = c0[j]; ls[s][4 + j] = c1[j];
    }
  }
  float M[8], den[8], acc[8];
#pragma unroll
  for (int j = 0; j < 8; ++j) M[j] = ms[0][j];
#pragma unroll
  for (int s = 1; s < S; ++s)
#pragma unroll
    for (int j = 0; j < 8; ++j) M[j] = fmaxf(M[j], ms[s][j]);
#pragma unroll
  for (int j = 0; j < 8; ++j) { den[j] = 0.f; acc[j] = 0.f; }
#pragma unroll
  for (int s = 0; s < S; ++s) {
    const f16* op = opart + (((size_t)s * Bn + b) * Dd + d) * Nn + nb;
    f16x8 ov = *(const f16x8*)op;
#pragma unroll
    for (int j = 0; j < 8; ++j) {
      float wgt = __expf(ms[s][j] - M[j]);
      den[j] += ls[s][j] * wgt;
      acc[j] += (float)ov[j] * wgt;
    }
  }
  float* po = out + ((size_t)b * Dd + d) * Nn + nb;
  f32x4 r0, r1;
#pragma unroll
  for (int j = 0; j < 4; ++j) {
    r0[j] = acc[j] / den[j];
    r1[j] = acc[4 + j] / den[4 + j];
  }
  *(f32x4*)po = r0;
  *(f32x4*)(po + 4) = r1;
}

// ---------------------------------------------------------------------------
extern "C" void kernel_launch(void* const* d_in, const int* in_sizes, int n_in,
                              void* d_out, int out_size, void* d_ws,
                              size_t ws_size, hipStream_t stream) {
  const float* x  = (const float*)d_in[0];
  const float* Wq = (const float*)d_in[1];
  const float* bq = (const float*)d_in[2];
  const float* Wk = (const float*)d_in[3];
  const float* bk = (const float*)d_in[4];
  const float* Wv = (const float*)d_in[5];
  const float* bv = (const float*)d_in[6];
  f16* ws = (f16*)d_ws;
  float* out = (float*)d_out;

  int S = 1, lgS = 0;
  {
    size_t need4 = (OFF_OP + 4ull * 8388608) * 2 + 4ull * 131072;
    size_t need2 = (OFF_OP + 2ull * 8388608) * 2 + 2ull * 131072;
    if (ws_size >= need4) { S = 4; lgS = 2; }
    else if (ws_size >= need2) { S = 2; lgS = 1; }
  }
  f16* opart = ws + OFF_OP;
  float* mbuf = (float*)(opart + (size_t)S * 8388608);
  float* lbuf = mbuf + (size_t)S * Bn * Nn;

  hipLaunchKernelGGL(wcvt_kernel, dim3(3072), dim3(256), 0, stream,
                     Wq, Wk, Wv, ws);
  hipLaunchKernelGGL(xt_kernel, dim3(Nn / 32, Dd / 32, Bn), dim3(256), 0,
                     stream, x, ws);
  hipLaunchKernelGGL(proj_kernel, dim3(Nn / 64, Bn, 3), dim3(256), 0, stream,
                     ws, bq, bk, bv);
  hipLaunchKernelGGL(attn_kernel, dim3(128 * S), dim3(512), 0, stream,
                     ws, opart, mbuf, lbuf, 32 / S, lgS);
  switch (S) {
    case 4:
      hipLaunchKernelGGL((merge_kernel<4>), dim3(4096), dim3(256), 0, stream,
                         opart, mbuf, lbuf, out);
      break;
    case 2:
      hipLaunchKernelGGL((merge_kernel<2>), dim3(4096), dim3(256), 0, stream,
                         opart, mbuf, lbuf, out);
      break;
    default:
      hipLaunchKernelGGL((merge_kernel<1>), dim3(4096), dim3(256), 0, stream,
                         opart, mbuf, lbuf, out);
      break;
  }
}